// Round 20
// baseline (995.295 us; speedup 1.0000x reference)
//
#include <hip/hip_runtime.h>
#include <math.h>

constexpr int BATCH = 4;
constexpr int NPTS  = 8192;
constexpr int KSEL  = 16;
constexpr int TILE  = 2048;

#define PI_F 3.14159265358979323846f

// Fusion barrier: value passes through an empty inline-asm VGPR constraint, becoming an
// INLINEASM-defined node the DAGCombiner cannot contract into an FMA. (hipcc's
// -ffp-contract=fast sets backend AllowFPOpFusion=Fast which fuses fadd(fmul,fmul)
// even when '#pragma clang fp contract(off)' strips IR flags; proven R12==R1/R8 etc.,
// and R17 vs R15 proved the barrier DOES change the executed chain.)
__device__ __forceinline__ float opaque(float v) { asm("" : "+v"(v)); return v; }

// ---------------- Kernel 1: features + encode (passed rounds 1-19; codegen untouched) --------
__global__ __launch_bounds__(256) void feat_encode_kernel(
    const float* __restrict__ coords, const float* __restrict__ demands,
    const float* __restrict__ capacity, const float* __restrict__ curpos,
    const float* __restrict__ Wa,  const float* __restrict__ ba,
    const float* __restrict__ W1,  const float* __restrict__ b1,
    const float* __restrict__ W2,  const float* __restrict__ b2,
    float* __restrict__ out_psi, float* __restrict__ out_feat)
{
    int gid = blockIdx.x * blockDim.x + threadIdx.x;
    if (gid >= BATCH * NPTS) return;
    int b = gid >> 13;

    float2 c   = ((const float2*)coords)[gid];
    float2 dep = ((const float2*)coords)[(size_t)b * NPTS];
    float2 cn  = ((const float2*)curpos)[b];

    float relx = c.x - dep.x, rely = c.y - dep.y;
    float dist_depot = sqrtf(relx * relx + rely * rely);
    float angle = atan2f(rely, relx) / PI_F;
    float dem = demands[gid] / capacity[b];
    float dcx = c.x - cn.x, dcy = c.y - cn.y;
    float dist_cur = sqrtf(dcx * dcx + dcy * dcy);

    float f0 = c.x, f1 = c.y, f2 = dem, f3 = dist_depot, f4 = angle, f5 = dist_cur;

    float p0 = ba[0] + f0*Wa[0] + f1*Wa[1] + f2*Wa[2]  + f3*Wa[3]  + f4*Wa[4]  + f5*Wa[5];
    float p1 = ba[1] + f0*Wa[6] + f1*Wa[7] + f2*Wa[8]  + f3*Wa[9]  + f4*Wa[10] + f5*Wa[11];
    float nrm = sqrtf(p0 * p0 + p1 * p1);
    float inv = 1.0f / (nrm + 1e-8f);
    float x = p0 * inv, y = p1 * inv;

    float theta = b2[0];
    #pragma unroll
    for (int j = 0; j < 16; ++j) {
        const float* w = W1 + j * 6;
        float hj = tanhf(b1[j] + f0*w[0] + f1*w[1] + f2*w[2] + f3*w[3] + f4*w[4] + f5*w[5]);
        theta += hj * W2[j];
    }
    float sth, cth;
    sincosf(theta, &sth, &cth);

    ((float2*)out_psi)[gid] = make_float2(cth * x - sth * y, sth * x + cth * y);
    float2* fo = (float2*)out_feat + (size_t)gid * 3;
    fo[0] = make_float2(f0, f1);
    fo[1] = make_float2(f2, f3);
    fo[2] = make_float2(f4, f5);
}

// ---------------- Kernel 2: brute 16-NN, TRUE (a,b,A1) chain, stable-low ties ---------------
// The BLAS-mirror chain — "sq via np.sum (unfused), dot via @ (sgemm FMA)" — which R14
// INTENDED but never executed (its unfused sq was silently contracted to (c) by the
// backend; proven by R14==R5 bit-identity). Now forced with asm barriers:
//   sq  = round32(x*x) + round32(y*y)              // (a): opaque products, unfused add
//   dot = fma32(y_i, y_j, round32(x_i*x_j))        // (b): opaque first product, real fma
//   d2  = round32(round32(sq_i+sq_j) - 2*dot)      // A1 (backend fma(-2,dot,t1) value-equal)
// Evidence: closest probe ever = (c,b)=7192, exactly one sq-rounding away from (a,b).
// R19 proved no gap-7688 tie exists (keyed probe never fired) -> (a,a) values are wrong,
// not its ties. Ties here: ascending-j strict-< = stable low-first (R18: the one known
// accurate-chain tie is ref-LOW).
__global__ __launch_bounds__(64) void knn_brute_kernel(
    const float* __restrict__ coords,    // B,N,2
    float* __restrict__ out_knn)         // B,N,16 (indices stored as floats)
{
    const int b = blockIdx.y;
    const int q = blockIdx.x * 64 + threadIdx.x;
    const float2* cb = (const float2*)coords + (size_t)b * NPTS;

    __shared__ float2 sxy[TILE];
    __shared__ float  ssq[TILE];

    float2 cq = cb[q];
    float xq = cq.x, yq = cq.y;
    float sqx = opaque(__fmul_rn(xq, xq));
    float sqy = opaque(__fmul_rn(yq, yq));
    float sqq = __fadd_rn(sqx, sqy);                      // truly unfused (a)-sq

    float bd[KSEL];
    int   bi[KSEL];
    #pragma unroll
    for (int p = 0; p < KSEL; ++p) { bd[p] = INFINITY; bi[p] = 0; }

    for (int t0 = 0; t0 < NPTS; t0 += TILE) {
        for (int t = threadIdx.x; t < TILE; t += 64) {
            float2 cc = cb[t0 + t];
            sxy[t] = cc;
            float sx = opaque(__fmul_rn(cc.x, cc.x));
            float sy = opaque(__fmul_rn(cc.y, cc.y));
            ssq[t] = __fadd_rn(sx, sy);                   // truly unfused (a)-sq
        }
        __syncthreads();

        #pragma unroll 4
        for (int t = 0; t < TILE; ++t) {
            const int j = t0 + t;
            float2 cj = sxy[t];                           // LDS broadcast
            float px  = opaque(__fmul_rn(xq, cj.x));      // round32(x_i*x_j), kept separate
            float dot = fmaf(yq, cj.y, px);               // (b)-dot: sgemm k-ascending FMA
            float d2  = __fsub_rn(__fadd_rn(sqq, ssq[t]), __fmul_rn(2.0f, dot)); // A1

            if (d2 < bd[KSEL - 1] && j != q) {            // strict: stable low-first ties
                bool lt[KSEL];
                #pragma unroll
                for (int k = 0; k < KSEL; ++k) lt[k] = d2 < bd[k];
                #pragma unroll
                for (int k = KSEL - 1; k >= 1; --k) {
                    bd[k] = lt[k-1] ? bd[k-1] : (lt[k] ? d2 : bd[k]);
                    bi[k] = lt[k-1] ? bi[k-1] : (lt[k] ? j  : bi[k]);
                }
                bd[0] = lt[0] ? d2 : bd[0];
                bi[0] = lt[0] ? j  : bi[0];
            }
        }
        __syncthreads();
    }

    float* o = out_knn + ((size_t)b * NPTS + q) * KSEL;
    #pragma unroll
    for (int k = 0; k < KSEL; ++k) o[k] = (float)bi[k];
}

// ---------------- launch ----------------
extern "C" void kernel_launch(void* const* d_in, const int* in_sizes, int n_in,
                              void* d_out, int out_size, void* d_ws, size_t ws_size,
                              hipStream_t stream) {
    const float* coords   = (const float*)d_in[0];
    const float* demands  = (const float*)d_in[1];
    const float* capacity = (const float*)d_in[2];
    const float* curpos   = (const float*)d_in[3];
    const float* Wa       = (const float*)d_in[4];
    const float* ba       = (const float*)d_in[5];
    const float* W1       = (const float*)d_in[6];
    const float* b1       = (const float*)d_in[7];
    const float* W2       = (const float*)d_in[8];
    const float* b2       = (const float*)d_in[9];
    // d_in[10] = knn_k (always 16, hardcoded)

    float* out      = (float*)d_out;
    float* out_psi  = out;                    // 4*8192*2  = 65536
    float* out_feat = out + 65536;            // 4*8192*6  = 196608
    float* out_knn  = out + 65536 + 196608;   // 4*8192*16 = 524288

    feat_encode_kernel<<<dim3((BATCH * NPTS) / 256), dim3(256), 0, stream>>>(
        coords, demands, capacity, curpos, Wa, ba, W1, b1, W2, b2, out_psi, out_feat);

    knn_brute_kernel<<<dim3(NPTS / 64, BATCH), dim3(64), 0, stream>>>(coords, out_knn);
}

// Round 21
// 174.385 us; speedup vs baseline: 5.7074x; 5.7074x over previous
//
#include <hip/hip_runtime.h>
#include <math.h>

constexpr int BATCH = 4;
constexpr int NPTS  = 8192;
constexpr int KSEL  = 16;
constexpr int G     = 64;        // grid cells per axis
constexpr int NC    = G * G;     // 4096 cells
#define CELL_W (1.0 / 64.0)

// ---- workspace layout (bytes) ----
constexpr size_t WS_HIST  = 0;        // BATCH*NC*4        = 65536
constexpr size_t WS_CURS  = 65536;    // BATCH*NC*4        = 65536
constexpr size_t WS_CSTRT = 131072;   // BATCH*(NC+1)*4    = 65552
constexpr size_t WS_PTS   = 262144;   // BATCH*NPTS*16     = 524288  (x,y,idx,sq)

#define PI_F 3.14159265358979323846f

// Fusion barrier (R17-proven): INLINEASM-defined value the DAGCombiner cannot
// contract into FMA (hipcc backend fuses fadd(fmul,fmul) even with contract(off)).
__device__ __forceinline__ float opaque(float v) { asm("" : "+v"(v)); return v; }

__device__ __forceinline__ int cell_of(float x) {
    int c = (int)(x * 64.0f);
    return c < 0 ? 0 : (c > 63 ? 63 : c);
}

// ---------------- Kernel 1: features + encode (passed rounds 1-20) ----------------
__global__ __launch_bounds__(256) void feat_encode_kernel(
    const float* __restrict__ coords, const float* __restrict__ demands,
    const float* __restrict__ capacity, const float* __restrict__ curpos,
    const float* __restrict__ Wa,  const float* __restrict__ ba,
    const float* __restrict__ W1,  const float* __restrict__ b1,
    const float* __restrict__ W2,  const float* __restrict__ b2,
    float* __restrict__ out_psi, float* __restrict__ out_feat)
{
    int gid = blockIdx.x * blockDim.x + threadIdx.x;
    if (gid >= BATCH * NPTS) return;
    int b = gid >> 13;

    float2 c   = ((const float2*)coords)[gid];
    float2 dep = ((const float2*)coords)[(size_t)b * NPTS];
    float2 cn  = ((const float2*)curpos)[b];

    float relx = c.x - dep.x, rely = c.y - dep.y;
    float dist_depot = sqrtf(relx * relx + rely * rely);
    float angle = atan2f(rely, relx) / PI_F;
    float dem = demands[gid] / capacity[b];
    float dcx = c.x - cn.x, dcy = c.y - cn.y;
    float dist_cur = sqrtf(dcx * dcx + dcy * dcy);

    float f0 = c.x, f1 = c.y, f2 = dem, f3 = dist_depot, f4 = angle, f5 = dist_cur;

    float p0 = ba[0] + f0*Wa[0] + f1*Wa[1] + f2*Wa[2]  + f3*Wa[3]  + f4*Wa[4]  + f5*Wa[5];
    float p1 = ba[1] + f0*Wa[6] + f1*Wa[7] + f2*Wa[8]  + f3*Wa[9]  + f4*Wa[10] + f5*Wa[11];
    float nrm = sqrtf(p0 * p0 + p1 * p1);
    float inv = 1.0f / (nrm + 1e-8f);
    float x = p0 * inv, y = p1 * inv;

    float theta = b2[0];
    #pragma unroll
    for (int j = 0; j < 16; ++j) {
        const float* w = W1 + j * 6;
        float hj = tanhf(b1[j] + f0*w[0] + f1*w[1] + f2*w[2] + f3*w[3] + f4*w[4] + f5*w[5]);
        theta += hj * W2[j];
    }
    float sth, cth;
    sincosf(theta, &sth, &cth);

    ((float2*)out_psi)[gid] = make_float2(cth * x - sth * y, sth * x + cth * y);
    float2* fo = (float2*)out_feat + (size_t)gid * 3;
    fo[0] = make_float2(f0, f1);
    fo[1] = make_float2(f2, f3);
    fo[2] = make_float2(f4, f5);
}

// ---------------- Grid build (enumeration verified bit-identical to brute in R2-R4) --------
__global__ __launch_bounds__(256) void hist_kernel(const float* __restrict__ coords,
                                                   int* __restrict__ hist)
{
    int gid = blockIdx.x * 256 + threadIdx.x;
    if (gid >= BATCH * NPTS) return;
    int b = gid >> 13;
    float2 c = ((const float2*)coords)[gid];
    atomicAdd(&hist[b * NC + cell_of(c.y) * G + cell_of(c.x)], 1);
}

__global__ __launch_bounds__(1024) void scan_kernel(const int* __restrict__ hist,
                                                    int* __restrict__ cellStart,
                                                    int* __restrict__ cursor)
{
    int b = blockIdx.x;
    int t = threadIdx.x;
    int lane = t & 63, wid = t >> 6;
    const int4* h4 = (const int4*)(hist + b * NC);
    int4 v = h4[t];
    int s = v.x + v.y + v.z + v.w;

    int inc = s;
    #pragma unroll
    for (int d = 1; d < 64; d <<= 1) {
        int o = __shfl_up(inc, d, 64);
        if (lane >= d) inc += o;
    }
    __shared__ int wsum[16];
    if (lane == 63) wsum[wid] = inc;
    __syncthreads();
    if (t < 16) {
        int winc = wsum[t];
        #pragma unroll
        for (int d = 1; d < 16; d <<= 1) {
            int o = __shfl_up(winc, d, 16);
            if (t >= d) winc += o;
        }
        wsum[t] = winc;
    }
    __syncthreads();
    int base = (wid ? wsum[wid - 1] : 0) + (inc - s);
    int e0 = base, e1 = e0 + v.x, e2 = e1 + v.y, e3 = e2 + v.z;
    int* cs = cellStart + b * (NC + 1);
    cs[4*t+0] = e0; cs[4*t+1] = e1; cs[4*t+2] = e2; cs[4*t+3] = e3;
    int* cu = cursor + b * NC;
    cu[4*t+0] = e0; cu[4*t+1] = e1; cu[4*t+2] = e2; cu[4*t+3] = e3;
    if (t == 1023) cs[NC] = e3 + v.w;
}

__global__ __launch_bounds__(256) void scatter_kernel(const float* __restrict__ coords,
                                                      int* __restrict__ cursor,
                                                      float4* __restrict__ pts)
{
    int gid = blockIdx.x * 256 + threadIdx.x;
    if (gid >= BATCH * NPTS) return;
    int b = gid >> 13, n = gid & (NPTS - 1);
    float2 c = ((const float2*)coords)[gid];
    // unfused (a)-sq, same chain as the verified R20 kernel
    float sx = opaque(__fmul_rn(c.x, c.x));
    float sy = opaque(__fmul_rn(c.y, c.y));
    float sq = __fadd_rn(sx, sy);
    int pos = atomicAdd(&cursor[b * NC + cell_of(c.y) * G + cell_of(c.x)], 1);
    pts[(b << 13) + pos] = make_float4(c.x, c.y, __int_as_float(n), sq);
}

// ---------------- Kernel 2: grid 16-NN, verified (a,b,A1) chain ----------------
// Chain (== R20's PASSING kernel, bit-exact):
//   sq  = round32(x*x) + round32(y*y)        // opaque products (precomputed in scatter)
//   dot = fma32(y_i, y_j, round32(x_i*x_j))  // opaque first product
//   d2  = round32(round32(sq_i+sq_j) - 2*dot)
// Ties: lexicographic (d2, j) strict compare = stable LOW-index-first, independent of
// scatter arrival order (grid<->brute bit-identity proven R2-R4).
// Termination: all unscanned points lie outside the scanned square; their chain-d2
// >= (R - 1e-7)^2 - 1e-6 > bd[15] once bd[15] <= (R-1e-7)^2 - 1e-5 (chain err <= ~1e-6
// per side, cell-assign slop <= 6e-8; 1e-5 margin = >5x safety, costs ~no extra rings).
__global__ __launch_bounds__(64) void knn_grid_kernel(
    const int* __restrict__ cellStart, const float4* __restrict__ pts,
    float* __restrict__ out_knn)
{
    const int b = blockIdx.y;
    const int p = blockIdx.x * 64 + threadIdx.x;   // sorted position = query
    const int* cs = cellStart + b * (NC + 1);
    const float4* pb = pts + ((size_t)b << 13);

    float4 me = pb[p];
    const float xq = me.x, yq = me.y, sqq = me.w;
    const int qorig = __float_as_int(me.z);
    const double xqd = (double)xq, yqd = (double)yq;
    const int cx = cell_of(xq), cy = cell_of(yq);

    float bd[KSEL];
    int   bi[KSEL];
    #pragma unroll
    for (int i = 0; i < KSEL; ++i) { bd[i] = INFINITY; bi[i] = 0x7fffffff; }

    auto scan_span = [&](int cbeg, int cend) {
        for (int t = cbeg; t < cend; ++t) {
            float4 pj = pb[t];
            int j = __float_as_int(pj.z);
            float px  = opaque(__fmul_rn(xq, pj.x));
            float dot = fmaf(yq, pj.y, px);
            float d2  = __fsub_rn(__fadd_rn(sqq, pj.w), __fmul_rn(2.0f, dot));
            if (j == qorig) continue;
            bool ins = (d2 < bd[KSEL-1]) || (d2 == bd[KSEL-1] && j < bi[KSEL-1]);
            if (ins) {
                bool lt[KSEL];
                #pragma unroll
                for (int k = 0; k < KSEL; ++k)
                    lt[k] = (d2 < bd[k]) || (d2 == bd[k] && j < bi[k]);
                #pragma unroll
                for (int k = KSEL - 1; k >= 1; --k) {
                    bd[k] = lt[k-1] ? bd[k-1] : (lt[k] ? d2 : bd[k]);
                    bi[k] = lt[k-1] ? bi[k-1] : (lt[k] ? j  : bi[k]);
                }
                bd[0] = lt[0] ? d2 : bd[0];
                bi[0] = lt[0] ? j  : bi[0];
            }
        }
    };

    bool done = false;
    for (int m = 0; m < G; ++m) {
        if (!done) {
            int x0 = max(cx - m, 0), x1 = min(cx + m, G - 1);
            if (cy - m >= 0)
                scan_span(cs[(cy - m) * G + x0], cs[(cy - m) * G + x1 + 1]);
            if (m > 0 && cy + m <= G - 1)
                scan_span(cs[(cy + m) * G + x0], cs[(cy + m) * G + x1 + 1]);
            if (m > 0) {
                int yA = max(cy - m + 1, 0), yB = min(cy + m - 1, G - 1);
                if (cx - m >= 0)
                    for (int yy = yA; yy <= yB; ++yy)
                        scan_span(cs[yy * G + (cx - m)], cs[yy * G + (cx - m) + 1]);
                if (cx + m <= G - 1)
                    for (int yy = yA; yy <= yB; ++yy)
                        scan_span(cs[yy * G + (cx + m)], cs[yy * G + (cx + m) + 1]);
            }
            double Rl = (cx - m > 0)     ? (xqd - (double)(cx - m) * CELL_W)     : INFINITY;
            double Rr = (cx + m < G - 1) ? ((double)(cx + m + 1) * CELL_W - xqd) : INFINITY;
            double Rb = (cy - m > 0)     ? (yqd - (double)(cy - m) * CELL_W)     : INFINITY;
            double Rt = (cy + m < G - 1) ? ((double)(cy + m + 1) * CELL_W - yqd) : INFINITY;
            double R  = fmin(fmin(Rl, Rr), fmin(Rb, Rt)) - 1e-7;
            if ((double)bd[KSEL-1] <= R * R - 1e-5) done = true;
        }
        if (__all(done)) break;
    }

    float* o = out_knn + ((size_t)b * NPTS + qorig) * KSEL;
    #pragma unroll
    for (int k = 0; k < KSEL; ++k) o[k] = (float)bi[k];
}

// ---------------- launch ----------------
extern "C" void kernel_launch(void* const* d_in, const int* in_sizes, int n_in,
                              void* d_out, int out_size, void* d_ws, size_t ws_size,
                              hipStream_t stream) {
    const float* coords   = (const float*)d_in[0];
    const float* demands  = (const float*)d_in[1];
    const float* capacity = (const float*)d_in[2];
    const float* curpos   = (const float*)d_in[3];
    const float* Wa       = (const float*)d_in[4];
    const float* ba       = (const float*)d_in[5];
    const float* W1       = (const float*)d_in[6];
    const float* b1       = (const float*)d_in[7];
    const float* W2       = (const float*)d_in[8];
    const float* b2       = (const float*)d_in[9];
    // d_in[10] = knn_k (always 16, hardcoded)

    float* out      = (float*)d_out;
    float* out_psi  = out;                    // 4*8192*2  = 65536
    float* out_feat = out + 65536;            // 4*8192*6  = 196608
    float* out_knn  = out + 65536 + 196608;   // 4*8192*16 = 524288

    int*    hist      = (int*)   ((char*)d_ws + WS_HIST);
    int*    cursor    = (int*)   ((char*)d_ws + WS_CURS);
    int*    cellStart = (int*)   ((char*)d_ws + WS_CSTRT);
    float4* pts       = (float4*)((char*)d_ws + WS_PTS);

    hipMemsetAsync(hist, 0, BATCH * NC * sizeof(int), stream);

    feat_encode_kernel<<<dim3((BATCH * NPTS) / 256), dim3(256), 0, stream>>>(
        coords, demands, capacity, curpos, Wa, ba, W1, b1, W2, b2, out_psi, out_feat);

    hist_kernel<<<dim3((BATCH * NPTS) / 256), dim3(256), 0, stream>>>(coords, hist);
    scan_kernel<<<dim3(BATCH), dim3(1024), 0, stream>>>(hist, cellStart, cursor);
    scatter_kernel<<<dim3((BATCH * NPTS) / 256), dim3(256), 0, stream>>>(coords, cursor, pts);

    knn_grid_kernel<<<dim3(NPTS / 64, BATCH), dim3(64), 0, stream>>>(cellStart, pts, out_knn);
}

// Round 22
// 148.933 us; speedup vs baseline: 6.6828x; 1.1709x over previous
//
#include <hip/hip_runtime.h>
#include <math.h>

constexpr int BATCH = 4;
constexpr int NPTS  = 8192;
constexpr int KSEL  = 16;
constexpr int G     = 64;        // grid cells per axis
constexpr int NC    = G * G;     // 4096 cells
#define CELL_W (1.0 / 64.0)

// ---- workspace layout (bytes) ----
constexpr size_t WS_HIST  = 0;        // BATCH*NC*4        = 65536
constexpr size_t WS_CURS  = 65536;    // BATCH*NC*4        = 65536
constexpr size_t WS_CSTRT = 131072;   // BATCH*(NC+1)*4    = 65552
constexpr size_t WS_PTS   = 262144;   // BATCH*NPTS*16     = 524288  (x,y,idx,sq)

#define PI_F 3.14159265358979323846f

// Fusion barrier (R17-proven): INLINEASM-defined value the DAGCombiner cannot
// contract into FMA (hipcc backend fuses fadd(fmul,fmul) even with contract(off)).
__device__ __forceinline__ float opaque(float v) { asm("" : "+v"(v)); return v; }

__device__ __forceinline__ int cell_of(float x) {
    int c = (int)(x * 64.0f);
    return c < 0 ? 0 : (c > 63 ? 63 : c);
}

// ---------------- Kernel 1: features + encode + histogram (fused) ----------------
__global__ __launch_bounds__(256) void feat_encode_hist_kernel(
    const float* __restrict__ coords, const float* __restrict__ demands,
    const float* __restrict__ capacity, const float* __restrict__ curpos,
    const float* __restrict__ Wa,  const float* __restrict__ ba,
    const float* __restrict__ W1,  const float* __restrict__ b1,
    const float* __restrict__ W2,  const float* __restrict__ b2,
    float* __restrict__ out_psi, float* __restrict__ out_feat,
    int* __restrict__ hist)
{
    int gid = blockIdx.x * blockDim.x + threadIdx.x;
    if (gid >= BATCH * NPTS) return;
    int b = gid >> 13;

    float2 c   = ((const float2*)coords)[gid];
    float2 dep = ((const float2*)coords)[(size_t)b * NPTS];
    float2 cn  = ((const float2*)curpos)[b];

    atomicAdd(&hist[b * NC + cell_of(c.y) * G + cell_of(c.x)], 1);

    float relx = c.x - dep.x, rely = c.y - dep.y;
    float dist_depot = sqrtf(relx * relx + rely * rely);
    float angle = atan2f(rely, relx) / PI_F;
    float dem = demands[gid] / capacity[b];
    float dcx = c.x - cn.x, dcy = c.y - cn.y;
    float dist_cur = sqrtf(dcx * dcx + dcy * dcy);

    float f0 = c.x, f1 = c.y, f2 = dem, f3 = dist_depot, f4 = angle, f5 = dist_cur;

    float p0 = ba[0] + f0*Wa[0] + f1*Wa[1] + f2*Wa[2]  + f3*Wa[3]  + f4*Wa[4]  + f5*Wa[5];
    float p1 = ba[1] + f0*Wa[6] + f1*Wa[7] + f2*Wa[8]  + f3*Wa[9]  + f4*Wa[10] + f5*Wa[11];
    float nrm = sqrtf(p0 * p0 + p1 * p1);
    float inv = 1.0f / (nrm + 1e-8f);
    float x = p0 * inv, y = p1 * inv;

    float theta = b2[0];
    #pragma unroll
    for (int j = 0; j < 16; ++j) {
        const float* w = W1 + j * 6;
        float hj = tanhf(b1[j] + f0*w[0] + f1*w[1] + f2*w[2] + f3*w[3] + f4*w[4] + f5*w[5]);
        theta += hj * W2[j];
    }
    float sth, cth;
    sincosf(theta, &sth, &cth);

    ((float2*)out_psi)[gid] = make_float2(cth * x - sth * y, sth * x + cth * y);
    float2* fo = (float2*)out_feat + (size_t)gid * 3;
    fo[0] = make_float2(f0, f1);
    fo[1] = make_float2(f2, f3);
    fo[2] = make_float2(f4, f5);
}

// ---------------- Grid build ----------------
__global__ __launch_bounds__(1024) void scan_kernel(const int* __restrict__ hist,
                                                    int* __restrict__ cellStart,
                                                    int* __restrict__ cursor)
{
    int b = blockIdx.x;
    int t = threadIdx.x;
    int lane = t & 63, wid = t >> 6;
    const int4* h4 = (const int4*)(hist + b * NC);
    int4 v = h4[t];
    int s = v.x + v.y + v.z + v.w;

    int inc = s;
    #pragma unroll
    for (int d = 1; d < 64; d <<= 1) {
        int o = __shfl_up(inc, d, 64);
        if (lane >= d) inc += o;
    }
    __shared__ int wsum[16];
    if (lane == 63) wsum[wid] = inc;
    __syncthreads();
    if (t < 16) {
        int winc = wsum[t];
        #pragma unroll
        for (int d = 1; d < 16; d <<= 1) {
            int o = __shfl_up(winc, d, 16);
            if (t >= d) winc += o;
        }
        wsum[t] = winc;
    }
    __syncthreads();
    int base = (wid ? wsum[wid - 1] : 0) + (inc - s);
    int e0 = base, e1 = e0 + v.x, e2 = e1 + v.y, e3 = e2 + v.z;
    int* cs = cellStart + b * (NC + 1);
    cs[4*t+0] = e0; cs[4*t+1] = e1; cs[4*t+2] = e2; cs[4*t+3] = e3;
    int* cu = cursor + b * NC;
    cu[4*t+0] = e0; cu[4*t+1] = e1; cu[4*t+2] = e2; cu[4*t+3] = e3;
    if (t == 1023) cs[NC] = e3 + v.w;
}

__global__ __launch_bounds__(256) void scatter_kernel(const float* __restrict__ coords,
                                                      int* __restrict__ cursor,
                                                      float4* __restrict__ pts)
{
    int gid = blockIdx.x * 256 + threadIdx.x;
    if (gid >= BATCH * NPTS) return;
    int b = gid >> 13, n = gid & (NPTS - 1);
    float2 c = ((const float2*)coords)[gid];
    float sx = opaque(__fmul_rn(c.x, c.x));
    float sy = opaque(__fmul_rn(c.y, c.y));
    float sq = __fadd_rn(sx, sy);                 // unfused (a)-sq, verified chain
    int pos = atomicAdd(&cursor[b * NC + cell_of(c.y) * G + cell_of(c.x)], 1);
    pts[(b << 13) + pos] = make_float4(c.x, c.y, __int_as_float(n), sq);
}

// ---------------- Kernel 2: grid 16-NN, 4 lanes per query ----------------
// Chain (== R20/R21's PASSING kernels, bit-exact): sq unfused, dot=fma(y,yj,round(x*xj)),
// d2 = (sqi+sqj) - 2*dot, lex (d2,j) stable-low ties.
// Parallelization: lanes l=0..3 of each aligned 4-lane group scan disjoint stride-4
// subsets of every span into private sorted top-16 lists; selection-merge (lex-exact)
// in LDS reproduces the serial result bit-identically.
// Termination bound: merged-16th <= min( min_l bd[15], max_l bd[3] ); the second term
// (union of four top-4s = 16 candidates) tracks the true r16, avoiding the r64 blowup
// a min-of-bd15-only rule would cause.
__global__ __launch_bounds__(64) void knn_grid_kernel(
    const int* __restrict__ cellStart, const float4* __restrict__ pts,
    float* __restrict__ out_knn)
{
    const int b = blockIdx.y;
    const int qslot = threadIdx.x >> 2;            // 16 queries per block
    const int l4 = threadIdx.x & 3;
    const int p = blockIdx.x * 16 + qslot;         // sorted position = query
    const int* cs = cellStart + b * (NC + 1);
    const float4* pb = pts + ((size_t)b << 13);

    float4 me = pb[p];
    const float xq = me.x, yq = me.y, sqq = me.w;
    const int qorig = __float_as_int(me.z);
    const double xqd = (double)xq, yqd = (double)yq;
    const int cx = cell_of(xq), cy = cell_of(yq);

    float bd[KSEL];
    int   bi[KSEL];
    #pragma unroll
    for (int i = 0; i < KSEL; ++i) { bd[i] = INFINITY; bi[i] = 0x7fffffff; }

    auto scan_span = [&](int cbeg, int cend) {
        for (int t = cbeg + l4; t < cend; t += 4) {
            float4 pj = pb[t];
            int j = __float_as_int(pj.z);
            float px  = opaque(__fmul_rn(xq, pj.x));
            float dot = fmaf(yq, pj.y, px);
            float d2  = __fsub_rn(__fadd_rn(sqq, pj.w), __fmul_rn(2.0f, dot));
            if (j == qorig) continue;
            bool ins = (d2 < bd[KSEL-1]) || (d2 == bd[KSEL-1] && j < bi[KSEL-1]);
            if (ins) {
                bool lt[KSEL];
                #pragma unroll
                for (int k = 0; k < KSEL; ++k)
                    lt[k] = (d2 < bd[k]) || (d2 == bd[k] && j < bi[k]);
                #pragma unroll
                for (int k = KSEL - 1; k >= 1; --k) {
                    bd[k] = lt[k-1] ? bd[k-1] : (lt[k] ? d2 : bd[k]);
                    bi[k] = lt[k-1] ? bi[k-1] : (lt[k] ? j  : bi[k]);
                }
                bd[0] = lt[0] ? d2 : bd[0];
                bi[0] = lt[0] ? j  : bi[0];
            }
        }
    };

    bool done = false;
    for (int m = 0; m < G; ++m) {
        if (!done) {
            int x0 = max(cx - m, 0), x1 = min(cx + m, G - 1);
            if (cy - m >= 0)
                scan_span(cs[(cy - m) * G + x0], cs[(cy - m) * G + x1 + 1]);
            if (m > 0 && cy + m <= G - 1)
                scan_span(cs[(cy + m) * G + x0], cs[(cy + m) * G + x1 + 1]);
            if (m > 0) {
                int yA = max(cy - m + 1, 0), yB = min(cy + m - 1, G - 1);
                if (cx - m >= 0)
                    for (int yy = yA; yy <= yB; ++yy)
                        scan_span(cs[yy * G + (cx - m)], cs[yy * G + (cx - m) + 1]);
                if (cx + m <= G - 1)
                    for (int yy = yA; yy <= yB; ++yy)
                        scan_span(cs[yy * G + (cx + m)], cs[yy * G + (cx + m) + 1]);
            }
            // cross-group bound on the merged 16th-best
            float t15 = bd[KSEL-1];
            t15 = fminf(t15, __shfl_xor(t15, 1));
            t15 = fminf(t15, __shfl_xor(t15, 2));
            float t3 = bd[3];
            t3 = fmaxf(t3, __shfl_xor(t3, 1));
            t3 = fmaxf(t3, __shfl_xor(t3, 2));
            float ub = fminf(t15, t3);

            double Rl = (cx - m > 0)     ? (xqd - (double)(cx - m) * CELL_W)     : INFINITY;
            double Rr = (cx + m < G - 1) ? ((double)(cx + m + 1) * CELL_W - xqd) : INFINITY;
            double Rb = (cy - m > 0)     ? (yqd - (double)(cy - m) * CELL_W)     : INFINITY;
            double Rt = (cy + m < G - 1) ? ((double)(cy + m + 1) * CELL_W - yqd) : INFINITY;
            double R  = fmin(fmin(Rl, Rr), fmin(Rb, Rt)) - 1e-7;
            if ((double)ub <= R * R - 1e-5) done = true;
        }
        if (__all(done)) break;
    }

    // ---- lex-exact 4-list selection merge in LDS ----
    __shared__ float sd[16][4][17];   // +1 pad: avoid 16-way bank conflict on q-stride
    __shared__ int   si[16][4][17];
    #pragma unroll
    for (int k = 0; k < KSEL; ++k) { sd[qslot][l4][k] = bd[k]; si[qslot][l4][k] = bi[k]; }
    __syncthreads();

    if (l4 == 0) {
        int h0 = 0, h1 = 0, h2 = 0, h3 = 0;
        float* o = out_knn + ((size_t)b * NPTS + qorig) * KSEL;
        for (int k = 0; k < KSEL; ++k) {
            float d0 = (h0 < KSEL) ? sd[qslot][0][h0] : INFINITY;
            int   i0 = (h0 < KSEL) ? si[qslot][0][h0] : 0x7fffffff;
            float d1 = (h1 < KSEL) ? sd[qslot][1][h1] : INFINITY;
            int   i1 = (h1 < KSEL) ? si[qslot][1][h1] : 0x7fffffff;
            float d2v = (h2 < KSEL) ? sd[qslot][2][h2] : INFINITY;
            int   i2 = (h2 < KSEL) ? si[qslot][2][h2] : 0x7fffffff;
            float d3 = (h3 < KSEL) ? sd[qslot][3][h3] : INFINITY;
            int   i3 = (h3 < KSEL) ? si[qslot][3][h3] : 0x7fffffff;

            bool b01 = (d1 < d0) || (d1 == d0 && i1 < i0);
            float dA = b01 ? d1 : d0; int iA = b01 ? i1 : i0; int wA = b01 ? 1 : 0;
            bool b23 = (d3 < d2v) || (d3 == d2v && i3 < i2);
            float dB = b23 ? d3 : d2v; int iB = b23 ? i3 : i2; int wB = b23 ? 3 : 2;
            bool bAB = (dB < dA) || (dB == dA && iB < iA);
            int w  = bAB ? wB : wA;
            int iw = bAB ? iB : iA;

            o[k] = (float)iw;
            if (w == 0) ++h0; else if (w == 1) ++h1; else if (w == 2) ++h2; else ++h3;
        }
    }
}

// ---------------- launch ----------------
extern "C" void kernel_launch(void* const* d_in, const int* in_sizes, int n_in,
                              void* d_out, int out_size, void* d_ws, size_t ws_size,
                              hipStream_t stream) {
    const float* coords   = (const float*)d_in[0];
    const float* demands  = (const float*)d_in[1];
    const float* capacity = (const float*)d_in[2];
    const float* curpos   = (const float*)d_in[3];
    const float* Wa       = (const float*)d_in[4];
    const float* ba       = (const float*)d_in[5];
    const float* W1       = (const float*)d_in[6];
    const float* b1       = (const float*)d_in[7];
    const float* W2       = (const float*)d_in[8];
    const float* b2       = (const float*)d_in[9];
    // d_in[10] = knn_k (always 16, hardcoded)

    float* out      = (float*)d_out;
    float* out_psi  = out;                    // 4*8192*2  = 65536
    float* out_feat = out + 65536;            // 4*8192*6  = 196608
    float* out_knn  = out + 65536 + 196608;   // 4*8192*16 = 524288

    int*    hist      = (int*)   ((char*)d_ws + WS_HIST);
    int*    cursor    = (int*)   ((char*)d_ws + WS_CURS);
    int*    cellStart = (int*)   ((char*)d_ws + WS_CSTRT);
    float4* pts       = (float4*)((char*)d_ws + WS_PTS);

    hipMemsetAsync(hist, 0, BATCH * NC * sizeof(int), stream);

    feat_encode_hist_kernel<<<dim3((BATCH * NPTS) / 256), dim3(256), 0, stream>>>(
        coords, demands, capacity, curpos, Wa, ba, W1, b1, W2, b2, out_psi, out_feat, hist);

    scan_kernel<<<dim3(BATCH), dim3(1024), 0, stream>>>(hist, cellStart, cursor);
    scatter_kernel<<<dim3((BATCH * NPTS) / 256), dim3(256), 0, stream>>>(coords, cursor, pts);

    knn_grid_kernel<<<dim3(NPTS / 16, BATCH), dim3(64), 0, stream>>>(cellStart, pts, out_knn);
}